// Round 10
// baseline (337.538 us; speedup 1.0000x reference)
//
#include <hip/hip_runtime.h>
#include <hip/hip_bf16.h>
#include <math.h>

// GATNet: hh = h@W_emb+b_emb -> GAT(8 heads,32,residual) -> GAT(1 head,32) -> out f32.
// Edge-feature branch of the reference is dead code (del e_feat) -> skipped.
// R10: dispatch-count 22 -> 11 (launch-gap ~10us each dominated R9):
//  - prep batches cvt + 3 B-swizzles; single memset (contiguous zero block)
//  - elr1 fused into fc1 epilogue (LDS C-tile); elr2 + bn_apply1(+residual) fused into fc2
//  - edge-weight computation fused into agg (ew arrays + dsts gone)
//  - bn_stats fused into agg epilogues (LDS reduce + per-block atomics)

#define HDIM 256
#define NHEADS 8
#define ODIM 32

typedef unsigned short u16;
typedef __attribute__((ext_vector_type(8))) short short8;
typedef __attribute__((ext_vector_type(4))) float f32x4;

__device__ __forceinline__ float bf2f(u16 u) { return __uint_as_float(((unsigned)u) << 16); }
__device__ __forceinline__ u16 f2bf(float f) {
    unsigned x = __float_as_uint(f);
    return (u16)((x + 0x7FFFu + ((x >> 16) & 1u)) >> 16);  // RNE
}

// ---------------- prep: batched cvt + B swizzles ----------------
// job 0: in_h f32 -> bf16. jobs 1-3: B[K][NC] f32 -> MFMA B-frag order bf16:
// Bsw[((ct*KB+kb)*64+lane)*8+j] = bf16(B[kb*32+(lane>>4)*8+j][ct*16+(lane&15)])
__global__ __launch_bounds__(256) void prep_kernel(const float* __restrict__ in_h, const float* __restrict__ W_emb,
                                                   const float* __restrict__ fc1, const float* __restrict__ fc2,
                                                   u16* __restrict__ Ah, u16* __restrict__ Bemb,
                                                   u16* __restrict__ Bfc1, u16* __restrict__ Bfc2, int n4) {
    int job = blockIdx.y;
    int idx = blockIdx.x * 256 + threadIdx.x;
    if (job == 0) {
        if (idx >= n4) return;
        float4 v = ((const float4*)in_h)[idx];
        ushort4 o = {f2bf(v.x), f2bf(v.y), f2bf(v.z), f2bf(v.w)};
        ((ushort4*)Ah)[idx] = o;
        return;
    }
    const float* B;
    u16* O;
    int K, NC;
    if (job == 1) { B = W_emb; O = Bemb; K = 128; NC = 256; }
    else if (job == 2) { B = fc1; O = Bfc1; K = 256; NC = 256; }
    else { B = fc2; O = Bfc2; K = 256; NC = 32; }
    int KB = K / 32;
    int TOT = (NC / 16) * KB * 64;
    if (idx >= TOT) return;
    int lane = idx & 63;
    int kb = (idx >> 6) % KB;
    int ct = (idx >> 6) / KB;
    int n = ct * 16 + (lane & 15);
    int k0 = kb * 32 + (lane >> 4) * 8;
    u16* dst = O + (size_t)idx * 8;
#pragma unroll
    for (int j = 0; j < 8; j++) dst[j] = f2bf(B[(size_t)(k0 + j) * NC + n]);
}

// ---------------- CSR build ----------------
__global__ __launch_bounds__(256) void deg_kernel(const int* __restrict__ dst, int* __restrict__ deg, int E, int N) {
    int i = blockIdx.x * 256 + threadIdx.x;
    if (i < E) {
        unsigned d = (unsigned)dst[i];
        if (d < (unsigned)N) atomicAdd(&deg[d], 1);
    }
}

__global__ __launch_bounds__(256) void scan_kernel(const int* __restrict__ deg, int* __restrict__ offs,
                                                   int* __restrict__ cursor, int n) {
    __shared__ int part[256];
    int t = threadIdx.x;
    int chunk = (n + 255) / 256;
    int lo = t * chunk, hi = lo + chunk;
    if (hi > n) hi = n;
    if (lo > n) lo = n;
    int s = 0;
    for (int i = lo; i < hi; i++) s += deg[i];
    part[t] = s;
    __syncthreads();
    if (t == 0) {
        int run = 0;
        for (int j = 0; j < 256; j++) { int v = part[j]; part[j] = run; run += v; }
        offs[n] = run;
    }
    __syncthreads();
    int run = part[t];
    for (int i = lo; i < hi; i++) {
        offs[i] = run;
        cursor[i] = run;
        run += deg[i];
    }
}

__global__ __launch_bounds__(256) void fill_kernel(const int* __restrict__ src, const int* __restrict__ dst,
                                                   int* __restrict__ cursor, int* __restrict__ srcs, int E, int N) {
    int i = blockIdx.x * 256 + threadIdx.x;
    if (i < E) {
        unsigned d = (unsigned)dst[i];
        if (d < (unsigned)N) {
            int p = atomicAdd(&cursor[d], 1);
            if ((unsigned)p < (unsigned)E) srcs[p] = src[i];
        }
    }
}

// ---------------- MFMA GEMM (generic, used for embedding) ----------------
template <int K, int NC, bool BIAS, typename OutT>
__global__ __launch_bounds__(256) void gemm_mfma(const u16* __restrict__ A, const u16* __restrict__ Bsw,
                                                 const float* __restrict__ bias, OutT* __restrict__ C, int M) {
    constexpr int KB = K / 32;
    constexpr int NCT = NC / 16;
    const int lane = threadIdx.x & 63;
    const int r0 = blockIdx.x * 64 + (threadIdx.x >> 6) * 16;
    if (r0 >= M) return;
    const int m = lane & 15, q = lane >> 4;
    const int row = r0 + m;
    short8 a[KB];
#pragma unroll
    for (int kb = 0; kb < KB; kb++) {
        if (row < M) a[kb] = *(const short8*)(A + (size_t)row * K + kb * 32 + q * 8);
        else a[kb] = (short8){0, 0, 0, 0, 0, 0, 0, 0};
    }
    const short8* B8 = (const short8*)Bsw;
#pragma unroll 1
    for (int ct = 0; ct < NCT; ct++) {
        f32x4 acc = {0.f, 0.f, 0.f, 0.f};
#pragma unroll
        for (int kb = 0; kb < KB; kb++)
            acc = __builtin_amdgcn_mfma_f32_16x16x32_bf16(a[kb], B8[(ct * KB + kb) * 64 + lane], acc, 0, 0, 0);
        float bv = BIAS ? bias[ct * 16 + m] : 0.f;
#pragma unroll
        for (int r = 0; r < 4; r++) {
            int ro = r0 + q * 4 + r;
            if (ro < M) {
                float v = acc[r] + bv;
                if constexpr (sizeof(OutT) == 2) C[(size_t)ro * NC + ct * 16 + m] = f2bf(v);
                else C[(size_t)ro * NC + ct * 16 + m] = v;
            }
        }
    }
}

// ---------------- fc1 GEMM + fused elr1 ----------------
__global__ __launch_bounds__(256) void gemm_fc1_elr(const u16* __restrict__ A, const u16* __restrict__ Bsw,
                                                    const float* __restrict__ al, const float* __restrict__ ar,
                                                    u16* __restrict__ featC, u16* __restrict__ el,
                                                    u16* __restrict__ er, int M) {
    __shared__ u16 tile[64][256];  // 32 KB
    const int lane = threadIdx.x & 63;
    const int wq = threadIdx.x >> 6;
    const int rb = blockIdx.x * 64;
    const int r0 = rb + wq * 16;
    const int m = lane & 15, q = lane >> 4;
    const int row = r0 + m;
    short8 a[8];
#pragma unroll
    for (int kb = 0; kb < 8; kb++) {
        if (row < M) a[kb] = *(const short8*)(A + (size_t)row * 256 + kb * 32 + q * 8);
        else a[kb] = (short8){0, 0, 0, 0, 0, 0, 0, 0};
    }
    const short8* B8 = (const short8*)Bsw;
#pragma unroll 1
    for (int ct = 0; ct < 16; ct++) {
        f32x4 acc = {0.f, 0.f, 0.f, 0.f};
#pragma unroll
        for (int kb = 0; kb < 8; kb++)
            acc = __builtin_amdgcn_mfma_f32_16x16x32_bf16(a[kb], B8[(ct * 8 + kb) * 64 + lane], acc, 0, 0, 0);
#pragma unroll
        for (int r = 0; r < 4; r++) {
            int rl = wq * 16 + q * 4 + r;
            int ro = rb + rl;
            u16 v = 0;
            if (ro < M) {
                v = f2bf(acc[r]);
                featC[(size_t)ro * 256 + ct * 16 + m] = v;
            }
            tile[rl][ct * 16 + m] = v;
        }
    }
    __syncthreads();
    // elr1: 64 nodes x 8 heads = 512 tasks
    int t = threadIdx.x;
#pragma unroll
    for (int task = t; task < 512; task += 256) {
        int nl = task >> 3, h = task & 7;
        int node = rb + nl;
        if (node >= M) continue;
        float a_ = 0.f, b_ = 0.f;
#pragma unroll
        for (int d = 0; d < 32; d++) {
            float fv = bf2f(tile[nl][h * 32 + d]);
            a_ += fv * al[h * 32 + d];
            b_ += fv * ar[h * 32 + d];
        }
        el[node * 8 + h] = f2bf(a_);
        er[node * 8 + h] = f2bf(b_);
    }
}

// exp(leaky_relu(l)); logits O(0.1), max-subtraction unnecessary (identical ratios)
__device__ __forceinline__ float edgew(float l) {
    l = (l > 0.f) ? l : 0.2f * l;
    l = fminf(fmaxf(l, -30.f), 30.f);
    return __expf(l);
}

// ---------------- agg1: fused edge weights + bn stats ----------------
// Wave per node (4 nodes/block); lane l: channels 4l..4l+3, head l>>3.
__global__ __launch_bounds__(256) void agg1_fused(const u16* __restrict__ feat, const u16* __restrict__ el,
                                                  const u16* __restrict__ er, const int* __restrict__ offs,
                                                  const int* __restrict__ srcs, u16* __restrict__ rst,
                                                  float* __restrict__ stats, int N, int E) {
    __shared__ float ss[4][256], ss2[4][256];
    const int w = threadIdx.x >> 6, lane = threadIdx.x & 63;
    const int node = blockIdx.x * 4 + w;
    const int h = lane >> 3;
    float o0 = 0.f, o1 = 0.f, o2 = 0.f, o3 = 0.f;
    if (node < N) {
        int beg = offs[node], end = offs[node + 1];
        if (beg < 0) beg = 0;
        if (end > E) end = E;
        float ern = bf2f(er[node * 8 + h]);
        float ax = 0.f, ay = 0.f, az = 0.f, aw = 0.f, sw = 0.f;
        int j = beg;
        int end4 = beg + ((end - beg) & ~3);
        for (; j < end4; j += 4) {  // 4-deep software pipeline: independent gather chains
            int s0 = srcs[j], s1 = srcs[j + 1], s2 = srcs[j + 2], s3 = srcs[j + 3];
            unsigned c0 = (unsigned)s0 < (unsigned)N, c1 = (unsigned)s1 < (unsigned)N;
            unsigned c2 = (unsigned)s2 < (unsigned)N, c3 = (unsigned)s3 < (unsigned)N;
            s0 = c0 ? s0 : 0; s1 = c1 ? s1 : 0; s2 = c2 ? s2 : 0; s3 = c3 ? s3 : 0;
            u16 e0 = el[s0 * 8 + h], e1 = el[s1 * 8 + h], e2 = el[s2 * 8 + h], e3 = el[s3 * 8 + h];
            ushort4 f0 = *(const ushort4*)(feat + (size_t)s0 * 256 + lane * 4);
            ushort4 f1 = *(const ushort4*)(feat + (size_t)s1 * 256 + lane * 4);
            ushort4 f2 = *(const ushort4*)(feat + (size_t)s2 * 256 + lane * 4);
            ushort4 f3 = *(const ushort4*)(feat + (size_t)s3 * 256 + lane * 4);
            float w0 = c0 ? edgew(bf2f(e0) + ern) : 0.f;
            float w1 = c1 ? edgew(bf2f(e1) + ern) : 0.f;
            float w2 = c2 ? edgew(bf2f(e2) + ern) : 0.f;
            float w3 = c3 ? edgew(bf2f(e3) + ern) : 0.f;
            sw += w0 + w1 + w2 + w3;
            ax += w0 * bf2f(f0.x) + w1 * bf2f(f1.x) + w2 * bf2f(f2.x) + w3 * bf2f(f3.x);
            ay += w0 * bf2f(f0.y) + w1 * bf2f(f1.y) + w2 * bf2f(f2.y) + w3 * bf2f(f3.y);
            az += w0 * bf2f(f0.z) + w1 * bf2f(f1.z) + w2 * bf2f(f2.z) + w3 * bf2f(f3.z);
            aw += w0 * bf2f(f0.w) + w1 * bf2f(f1.w) + w2 * bf2f(f2.w) + w3 * bf2f(f3.w);
        }
        for (; j < end; j++) {
            int s = srcs[j];
            if ((unsigned)s >= (unsigned)N) continue;
            float wv = edgew(bf2f(el[s * 8 + h]) + ern);
            ushort4 f4 = *(const ushort4*)(feat + (size_t)s * 256 + lane * 4);
            sw += wv;
            ax += wv * bf2f(f4.x);
            ay += wv * bf2f(f4.y);
            az += wv * bf2f(f4.z);
            aw += wv * bf2f(f4.w);
        }
        float inv = 1.f / (sw + 1e-16f);
        ushort4 o;
        o.x = f2bf(ax * inv); o.y = f2bf(ay * inv); o.z = f2bf(az * inv); o.w = f2bf(aw * inv);
        *(ushort4*)(rst + (size_t)node * 256 + lane * 4) = o;
        o0 = bf2f(o.x); o1 = bf2f(o.y); o2 = bf2f(o.z); o3 = bf2f(o.w);
    }
    // block-level bn stats (rounded values, matching separate-kernel semantics)
    *(float4*)&ss[w][lane * 4] = make_float4(o0, o1, o2, o3);
    *(float4*)&ss2[w][lane * 4] = make_float4(o0 * o0, o1 * o1, o2 * o2, o3 * o3);
    __syncthreads();
    int t = threadIdx.x;
    float s = ss[0][t] + ss[1][t] + ss[2][t] + ss[3][t];
    float s2 = ss2[0][t] + ss2[1][t] + ss2[2][t] + ss2[3][t];
    atomicAdd(&stats[t], s);
    atomicAdd(&stats[256 + t], s2);
}

// ---------------- fc2 GEMM with fused bn_apply1(+residual) on A, + fused elr2 ----------------
__global__ __launch_bounds__(256) void gemm_fc2_fused(const u16* __restrict__ rst, const u16* __restrict__ hh,
                                                      const float* __restrict__ stats, const float* __restrict__ g,
                                                      const float* __restrict__ b, const u16* __restrict__ Bsw,
                                                      const float* __restrict__ al2, const float* __restrict__ ar2,
                                                      float* __restrict__ feat2, float* __restrict__ el2,
                                                      float* __restrict__ er2, int M, float invN) {
    __shared__ float sc[256], sh[256];
    __shared__ float tile[64][32];
    const int t = threadIdx.x;
    {   // per-channel scale/shift from batch stats
        float mu = stats[t] * invN;
        float var = fmaxf(stats[256 + t] * invN - mu * mu, 0.f);
        float s = g[t] * rsqrtf(var + 1e-5f);
        sc[t] = s;
        sh[t] = b[t] - mu * s;
    }
    __syncthreads();
    const int lane = t & 63, wq = t >> 6;
    const int rb = blockIdx.x * 64;
    const int m = lane & 15, q = lane >> 4;
    const int row = rb + wq * 16 + m;
    short8 a[8];
#pragma unroll
    for (int kb = 0; kb < 8; kb++) {
        if (row < M) {
            int k0 = kb * 32 + q * 8;
            ushort4 r01 = *(const ushort4*)(rst + (size_t)row * 256 + k0);
            ushort4 r23 = *(const ushort4*)(rst + (size_t)row * 256 + k0 + 4);
            ushort4 h01 = *(const ushort4*)(hh + (size_t)row * 256 + k0);
            ushort4 h23 = *(const ushort4*)(hh + (size_t)row * 256 + k0 + 4);
            u16 rv[8] = {r01.x, r01.y, r01.z, r01.w, r23.x, r23.y, r23.z, r23.w};
            u16 hv[8] = {h01.x, h01.y, h01.z, h01.w, h23.x, h23.y, h23.z, h23.w};
            short8 av;
#pragma unroll
            for (int j = 0; j < 8; j++) {
                int c = k0 + j;
                float y = sc[c] * bf2f(rv[j]) + sh[c];
                y = (y > 0.f) ? y : expm1f(y);               // elu
                av[j] = (short)f2bf(bf2f(hv[j]) + y);        // + residual, same rounding as before
            }
            a[kb] = av;
        } else a[kb] = (short8){0, 0, 0, 0, 0, 0, 0, 0};
    }
    const short8* B8 = (const short8*)Bsw;
#pragma unroll
    for (int ct = 0; ct < 2; ct++) {
        f32x4 acc = {0.f, 0.f, 0.f, 0.f};
#pragma unroll
        for (int kb = 0; kb < 8; kb++)
            acc = __builtin_amdgcn_mfma_f32_16x16x32_bf16(a[kb], B8[(ct * 8 + kb) * 64 + lane], acc, 0, 0, 0);
#pragma unroll
        for (int r = 0; r < 4; r++) {
            int rl = wq * 16 + q * 4 + r;
            int ro = rb + rl;
            float v = 0.f;
            if (ro < M) {
                v = acc[r];
                feat2[(size_t)ro * 32 + ct * 16 + m] = v;
            }
            tile[rl][ct * 16 + m] = v;
        }
    }
    __syncthreads();
    if (t < 64) {
        int node = rb + t;
        if (node < M) {
            float a_ = 0.f, b_ = 0.f;
#pragma unroll
            for (int d = 0; d < 32; d++) {
                float fv = tile[t][d];
                a_ += fv * al2[d];
                b_ += fv * ar2[d];
            }
            el2[node] = a_;
            er2[node] = b_;
        }
    }
}

// ---------------- agg2: fused edge weights + bn stats ----------------
__global__ __launch_bounds__(256) void agg2_fused(const float* __restrict__ feat, const float* __restrict__ el,
                                                  const float* __restrict__ er, const int* __restrict__ offs,
                                                  const int* __restrict__ srcs, float* __restrict__ rst,
                                                  float* __restrict__ stats, int N, int E) {
    __shared__ float ss[8][32], ss2[8][32];
    const int t = threadIdx.x;
    const int wn = t >> 5, d = t & 31;
    const int node = blockIdx.x * 8 + wn;
    float val = 0.f;
    if (node < N) {
        int beg = offs[node], end = offs[node + 1];
        if (beg < 0) beg = 0;
        if (end > E) end = E;
        float ern = er[node];
        float acc = 0.f, sw = 0.f;
#pragma unroll 2
        for (int j = beg; j < end; j++) {
            int s = srcs[j];
            if ((unsigned)s >= (unsigned)N) continue;
            float wv = edgew(el[s] + ern);
            sw += wv;
            acc += wv * feat[(size_t)s * 32 + d];
        }
        val = acc / (sw + 1e-16f);
        rst[(size_t)node * 32 + d] = val;
    }
    ss[wn][d] = val;
    ss2[wn][d] = val * val;
    __syncthreads();
    if (t < 32) {
        float s = 0.f, s2 = 0.f;
#pragma unroll
        for (int w = 0; w < 8; w++) { s += ss[w][t]; s2 += ss2[w][t]; }
        atomicAdd(&stats[t], s);
        atomicAdd(&stats[32 + t], s2);
    }
}

// ---------------- final bn + elu -> f32 out ----------------
__global__ __launch_bounds__(256) void bn_apply2(const float* __restrict__ rst, const float* __restrict__ stats,
                                                 const float* __restrict__ g, const float* __restrict__ b,
                                                 float* __restrict__ out, int total, float invN) {
    int idx = blockIdx.x * 256 + threadIdx.x;
    if (idx >= total) return;
    int c = idx & 31;
    float mu = stats[c] * invN;
    float var = fmaxf(stats[32 + c] * invN - mu * mu, 0.f);
    float y = g[c] * (rst[idx] - mu) * rsqrtf(var + 1e-5f) + b[c];
    y = (y > 0.f) ? y : expm1f(y);
    out[idx] = y;
}

extern "C" void kernel_launch(void* const* d_in, const int* in_sizes, int n_in, void* d_out, int out_size, void* d_ws,
                              size_t ws_size, hipStream_t stream) {
    const int N = out_size / ODIM;
    const int E = in_sizes[2];

    const int* src = (const int*)d_in[2];
    const int* dst = (const int*)d_in[3];
    const float* in_h = (const float*)d_in[0];
    const float* W_emb = (const float*)d_in[4];  const float* b_emb = (const float*)d_in[5];
    const float* fc1 = (const float*)d_in[18];   const float* al1 = (const float*)d_in[19];
    const float* ar1 = (const float*)d_in[20];
    const float* g1 = (const float*)d_in[21];    const float* b1 = (const float*)d_in[22];
    const float* fc2 = (const float*)d_in[23];   const float* al2 = (const float*)d_in[24];
    const float* ar2 = (const float*)d_in[25];
    const float* g2 = (const float*)d_in[26];    const float* b2 = (const float*)d_in[27];
    float* out = (float*)d_out;

    // ---- ws layout (~26 MB; ws is 268 MB per fill counters) ----
    char* base = (char*)d_ws;
    size_t off = 0;
    auto alloc = [&](size_t bytes) { void* p = base + off; off += (bytes + 63) & ~63ull; return p; };
    // contiguous zero block: deg[N] + stats[512] + stats2[64]
    char* zb   = (char*)alloc((size_t)N * 4 + 512 * 4 + 64 * 4);
    int* deg   = (int*)zb;
    float* stats  = (float*)(zb + (size_t)N * 4);
    float* stats2 = stats + 512;
    int* offs  = (int*)alloc((size_t)(N + 1) * 4);
    int* cursor = (int*)alloc((size_t)N * 4);
    int* srcs  = (int*)alloc((size_t)E * 4);
    u16* Ah    = (u16*)alloc((size_t)N * 128 * 2);
    u16* Bemb  = (u16*)alloc((size_t)128 * 256 * 2);
    u16* Bfc1  = (u16*)alloc((size_t)256 * 256 * 2);
    u16* Bfc2  = (u16*)alloc((size_t)256 * 32 * 2);
    u16* hh    = (u16*)alloc((size_t)N * HDIM * 2);
    u16* feat1 = (u16*)alloc((size_t)N * HDIM * 2);
    u16* el1   = (u16*)alloc((size_t)N * 8 * 2);
    u16* er1   = (u16*)alloc((size_t)N * 8 * 2);
    u16* rst   = (u16*)alloc((size_t)N * HDIM * 2);
    float* feat2 = (float*)alloc((size_t)N * 32 * 4);
    float* el2 = (float*)alloc((size_t)N * 4);
    float* er2 = (float*)alloc((size_t)N * 4);
    float* rst2 = (float*)alloc((size_t)N * 32 * 4);

    const int NB64 = (N + 63) / 64;

    // 1. zero accumulators (one memset)
    hipMemsetAsync(zb, 0, (size_t)N * 4 + 512 * 4 + 64 * 4, stream);
    // 2. prep: cvt in_h + swizzle 3 B matrices
    prep_kernel<<<dim3((N * 128 / 4 + 255) / 256, 4), 256, 0, stream>>>(in_h, W_emb, fc1, fc2, Ah, Bemb, Bfc1, Bfc2,
                                                                        N * 128 / 4);
    // 3-5. CSR by dst
    deg_kernel<<<(E + 255) / 256, 256, 0, stream>>>(dst, deg, E, N);
    scan_kernel<<<1, 256, 0, stream>>>(deg, offs, cursor, N);
    fill_kernel<<<(E + 255) / 256, 256, 0, stream>>>(src, dst, cursor, srcs, E, N);
    // 6. embedding
    gemm_mfma<128, 256, true, u16><<<NB64, 256, 0, stream>>>(Ah, Bemb, b_emb, hh, N);
    // 7. fc1 + elr1
    gemm_fc1_elr<<<NB64, 256, 0, stream>>>(hh, Bfc1, al1, ar1, feat1, el1, er1, N);
    // 8. agg1 (+ew +stats)
    agg1_fused<<<(N + 3) / 4, 256, 0, stream>>>(feat1, el1, er1, offs, srcs, rst, stats, N, E);
    // 9. fc2 (+bn_apply1+residual on A, +elr2)
    gemm_fc2_fused<<<NB64, 256, 0, stream>>>(rst, hh, stats, g1, b1, Bfc2, al2, ar2, feat2, el2, er2, N, 1.f / N);
    // 10. agg2 (+ew +stats)
    agg2_fused<<<(N + 7) / 8, 256, 0, stream>>>(feat2, el2, er2, offs, srcs, rst2, stats2, N, E);
    // 11. final bn -> out
    bn_apply2<<<(N * ODIM + 255) / 256, 256, 0, stream>>>(rst2, stats2, g2, b2, out, N * ODIM, 1.f / N);
}

// Round 11
// 287.338 us; speedup vs baseline: 1.1747x; 1.1747x over previous
//
#include <hip/hip_runtime.h>
#include <hip/hip_bf16.h>
#include <math.h>

// GATNet: hh = h@W_emb+b_emb -> GAT(8 heads,32,residual) -> GAT(1 head,32) -> out f32.
// Edge-feature branch of the reference is dead code (del e_feat) -> skipped.
// R11: revert ONLY the bn_stats-into-agg fusion (R10 regression: 2500 blocks x 512
// contended atomics = 1.28M ops on 32 cache lines -> agg1 68.7us). Keep ew-into-agg,
// elr1-into-fc1, bn_apply1+residual+elr2-into-fc2, batched prep, single memset.

#define HDIM 256
#define NHEADS 8
#define ODIM 32

typedef unsigned short u16;
typedef __attribute__((ext_vector_type(8))) short short8;
typedef __attribute__((ext_vector_type(4))) float f32x4;

__device__ __forceinline__ float bf2f(u16 u) { return __uint_as_float(((unsigned)u) << 16); }
__device__ __forceinline__ u16 f2bf(float f) {
    unsigned x = __float_as_uint(f);
    return (u16)((x + 0x7FFFu + ((x >> 16) & 1u)) >> 16);  // RNE
}

// ---------------- prep: batched cvt + B swizzles ----------------
__global__ __launch_bounds__(256) void prep_kernel(const float* __restrict__ in_h, const float* __restrict__ W_emb,
                                                   const float* __restrict__ fc1, const float* __restrict__ fc2,
                                                   u16* __restrict__ Ah, u16* __restrict__ Bemb,
                                                   u16* __restrict__ Bfc1, u16* __restrict__ Bfc2, int n4) {
    int job = blockIdx.y;
    int idx = blockIdx.x * 256 + threadIdx.x;
    if (job == 0) {
        if (idx >= n4) return;
        float4 v = ((const float4*)in_h)[idx];
        ushort4 o = {f2bf(v.x), f2bf(v.y), f2bf(v.z), f2bf(v.w)};
        ((ushort4*)Ah)[idx] = o;
        return;
    }
    const float* B;
    u16* O;
    int K, NC;
    if (job == 1) { B = W_emb; O = Bemb; K = 128; NC = 256; }
    else if (job == 2) { B = fc1; O = Bfc1; K = 256; NC = 256; }
    else { B = fc2; O = Bfc2; K = 256; NC = 32; }
    int KB = K / 32;
    int TOT = (NC / 16) * KB * 64;
    if (idx >= TOT) return;
    int lane = idx & 63;
    int kb = (idx >> 6) % KB;
    int ct = (idx >> 6) / KB;
    int n = ct * 16 + (lane & 15);
    int k0 = kb * 32 + (lane >> 4) * 8;
    u16* dst = O + (size_t)idx * 8;
#pragma unroll
    for (int j = 0; j < 8; j++) dst[j] = f2bf(B[(size_t)(k0 + j) * NC + n]);
}

// ---------------- CSR build ----------------
__global__ __launch_bounds__(256) void deg_kernel(const int* __restrict__ dst, int* __restrict__ deg, int E, int N) {
    int i = blockIdx.x * 256 + threadIdx.x;
    if (i < E) {
        unsigned d = (unsigned)dst[i];
        if (d < (unsigned)N) atomicAdd(&deg[d], 1);
    }
}

__global__ __launch_bounds__(256) void scan_kernel(const int* __restrict__ deg, int* __restrict__ offs,
                                                   int* __restrict__ cursor, int n) {
    __shared__ int part[256];
    int t = threadIdx.x;
    int chunk = (n + 255) / 256;
    int lo = t * chunk, hi = lo + chunk;
    if (hi > n) hi = n;
    if (lo > n) lo = n;
    int s = 0;
    for (int i = lo; i < hi; i++) s += deg[i];
    part[t] = s;
    __syncthreads();
    if (t == 0) {
        int run = 0;
        for (int j = 0; j < 256; j++) { int v = part[j]; part[j] = run; run += v; }
        offs[n] = run;
    }
    __syncthreads();
    int run = part[t];
    for (int i = lo; i < hi; i++) {
        offs[i] = run;
        cursor[i] = run;
        run += deg[i];
    }
}

__global__ __launch_bounds__(256) void fill_kernel(const int* __restrict__ src, const int* __restrict__ dst,
                                                   int* __restrict__ cursor, int* __restrict__ srcs, int E, int N) {
    int i = blockIdx.x * 256 + threadIdx.x;
    if (i < E) {
        unsigned d = (unsigned)dst[i];
        if (d < (unsigned)N) {
            int p = atomicAdd(&cursor[d], 1);
            if ((unsigned)p < (unsigned)E) srcs[p] = src[i];
        }
    }
}

// ---------------- MFMA GEMM (embedding) ----------------
template <int K, int NC, bool BIAS, typename OutT>
__global__ __launch_bounds__(256) void gemm_mfma(const u16* __restrict__ A, const u16* __restrict__ Bsw,
                                                 const float* __restrict__ bias, OutT* __restrict__ C, int M) {
    constexpr int KB = K / 32;
    constexpr int NCT = NC / 16;
    const int lane = threadIdx.x & 63;
    const int r0 = blockIdx.x * 64 + (threadIdx.x >> 6) * 16;
    if (r0 >= M) return;
    const int m = lane & 15, q = lane >> 4;
    const int row = r0 + m;
    short8 a[KB];
#pragma unroll
    for (int kb = 0; kb < KB; kb++) {
        if (row < M) a[kb] = *(const short8*)(A + (size_t)row * K + kb * 32 + q * 8);
        else a[kb] = (short8){0, 0, 0, 0, 0, 0, 0, 0};
    }
    const short8* B8 = (const short8*)Bsw;
#pragma unroll 1
    for (int ct = 0; ct < NCT; ct++) {
        f32x4 acc = {0.f, 0.f, 0.f, 0.f};
#pragma unroll
        for (int kb = 0; kb < KB; kb++)
            acc = __builtin_amdgcn_mfma_f32_16x16x32_bf16(a[kb], B8[(ct * KB + kb) * 64 + lane], acc, 0, 0, 0);
        float bv = BIAS ? bias[ct * 16 + m] : 0.f;
#pragma unroll
        for (int r = 0; r < 4; r++) {
            int ro = r0 + q * 4 + r;
            if (ro < M) {
                float v = acc[r] + bv;
                if constexpr (sizeof(OutT) == 2) C[(size_t)ro * NC + ct * 16 + m] = f2bf(v);
                else C[(size_t)ro * NC + ct * 16 + m] = v;
            }
        }
    }
}

// ---------------- fc1 GEMM + fused elr1 ----------------
__global__ __launch_bounds__(256) void gemm_fc1_elr(const u16* __restrict__ A, const u16* __restrict__ Bsw,
                                                    const float* __restrict__ al, const float* __restrict__ ar,
                                                    u16* __restrict__ featC, u16* __restrict__ el,
                                                    u16* __restrict__ er, int M) {
    __shared__ u16 tile[64][256];  // 32 KB
    const int lane = threadIdx.x & 63;
    const int wq = threadIdx.x >> 6;
    const int rb = blockIdx.x * 64;
    const int r0 = rb + wq * 16;
    const int m = lane & 15, q = lane >> 4;
    const int row = r0 + m;
    short8 a[8];
#pragma unroll
    for (int kb = 0; kb < 8; kb++) {
        if (row < M) a[kb] = *(const short8*)(A + (size_t)row * 256 + kb * 32 + q * 8);
        else a[kb] = (short8){0, 0, 0, 0, 0, 0, 0, 0};
    }
    const short8* B8 = (const short8*)Bsw;
#pragma unroll 1
    for (int ct = 0; ct < 16; ct++) {
        f32x4 acc = {0.f, 0.f, 0.f, 0.f};
#pragma unroll
        for (int kb = 0; kb < 8; kb++)
            acc = __builtin_amdgcn_mfma_f32_16x16x32_bf16(a[kb], B8[(ct * 8 + kb) * 64 + lane], acc, 0, 0, 0);
#pragma unroll
        for (int r = 0; r < 4; r++) {
            int rl = wq * 16 + q * 4 + r;
            int ro = rb + rl;
            u16 v = 0;
            if (ro < M) {
                v = f2bf(acc[r]);
                featC[(size_t)ro * 256 + ct * 16 + m] = v;
            }
            tile[rl][ct * 16 + m] = v;
        }
    }
    __syncthreads();
    int t = threadIdx.x;
#pragma unroll
    for (int task = t; task < 512; task += 256) {
        int nl = task >> 3, h = task & 7;
        int node = rb + nl;
        if (node >= M) continue;
        float a_ = 0.f, b_ = 0.f;
#pragma unroll
        for (int d = 0; d < 32; d++) {
            float fv = bf2f(tile[nl][h * 32 + d]);
            a_ += fv * al[h * 32 + d];
            b_ += fv * ar[h * 32 + d];
        }
        el[node * 8 + h] = f2bf(a_);
        er[node * 8 + h] = f2bf(b_);
    }
}

// exp(leaky_relu(l)); logits O(0.1), max-subtraction unnecessary (identical ratios)
__device__ __forceinline__ float edgew(float l) {
    l = (l > 0.f) ? l : 0.2f * l;
    l = fminf(fmaxf(l, -30.f), 30.f);
    return __expf(l);
}

// ---------------- agg1: fused edge weights (NO stats fusion) ----------------
__global__ __launch_bounds__(256) void agg1_fused(const u16* __restrict__ feat, const u16* __restrict__ el,
                                                  const u16* __restrict__ er, const int* __restrict__ offs,
                                                  const int* __restrict__ srcs, u16* __restrict__ rst, int N, int E) {
    const int node = blockIdx.x * 4 + (threadIdx.x >> 6);
    const int lane = threadIdx.x & 63;
    if (node >= N) return;
    const int h = lane >> 3;
    int beg = offs[node], end = offs[node + 1];
    if (beg < 0) beg = 0;
    if (end > E) end = E;
    float ern = bf2f(er[node * 8 + h]);
    float ax = 0.f, ay = 0.f, az = 0.f, aw = 0.f, sw = 0.f;
    int j = beg;
    int end4 = beg + ((end - beg) & ~3);
    for (; j < end4; j += 4) {  // 4-deep software pipeline
        int s0 = srcs[j], s1 = srcs[j + 1], s2 = srcs[j + 2], s3 = srcs[j + 3];
        unsigned c0 = (unsigned)s0 < (unsigned)N, c1 = (unsigned)s1 < (unsigned)N;
        unsigned c2 = (unsigned)s2 < (unsigned)N, c3 = (unsigned)s3 < (unsigned)N;
        s0 = c0 ? s0 : 0; s1 = c1 ? s1 : 0; s2 = c2 ? s2 : 0; s3 = c3 ? s3 : 0;
        u16 e0 = el[s0 * 8 + h], e1 = el[s1 * 8 + h], e2 = el[s2 * 8 + h], e3 = el[s3 * 8 + h];
        ushort4 f0 = *(const ushort4*)(feat + (size_t)s0 * 256 + lane * 4);
        ushort4 f1 = *(const ushort4*)(feat + (size_t)s1 * 256 + lane * 4);
        ushort4 f2 = *(const ushort4*)(feat + (size_t)s2 * 256 + lane * 4);
        ushort4 f3 = *(const ushort4*)(feat + (size_t)s3 * 256 + lane * 4);
        float w0 = c0 ? edgew(bf2f(e0) + ern) : 0.f;
        float w1 = c1 ? edgew(bf2f(e1) + ern) : 0.f;
        float w2 = c2 ? edgew(bf2f(e2) + ern) : 0.f;
        float w3 = c3 ? edgew(bf2f(e3) + ern) : 0.f;
        sw += w0 + w1 + w2 + w3;
        ax += w0 * bf2f(f0.x) + w1 * bf2f(f1.x) + w2 * bf2f(f2.x) + w3 * bf2f(f3.x);
        ay += w0 * bf2f(f0.y) + w1 * bf2f(f1.y) + w2 * bf2f(f2.y) + w3 * bf2f(f3.y);
        az += w0 * bf2f(f0.z) + w1 * bf2f(f1.z) + w2 * bf2f(f2.z) + w3 * bf2f(f3.z);
        aw += w0 * bf2f(f0.w) + w1 * bf2f(f1.w) + w2 * bf2f(f2.w) + w3 * bf2f(f3.w);
    }
    for (; j < end; j++) {
        int s = srcs[j];
        if ((unsigned)s >= (unsigned)N) continue;
        float wv = edgew(bf2f(el[s * 8 + h]) + ern);
        ushort4 f4 = *(const ushort4*)(feat + (size_t)s * 256 + lane * 4);
        sw += wv;
        ax += wv * bf2f(f4.x);
        ay += wv * bf2f(f4.y);
        az += wv * bf2f(f4.z);
        aw += wv * bf2f(f4.w);
    }
    float inv = 1.f / (sw + 1e-16f);
    ushort4 o;
    o.x = f2bf(ax * inv); o.y = f2bf(ay * inv); o.z = f2bf(az * inv); o.w = f2bf(aw * inv);
    *(ushort4*)(rst + (size_t)node * 256 + lane * 4) = o;
}

// ---------------- bn stats, separate low-contention kernels ----------------
__global__ __launch_bounds__(256) void bn_stats256(const u16* __restrict__ X, float* __restrict__ stats,
                                                   int rows, int RPB) {
    int t = threadIdx.x;
    int rbeg = blockIdx.x * RPB;
    int rend = rbeg + RPB;
    if (rend > rows) rend = rows;
    float s = 0.f, s2 = 0.f;
    for (int r = rbeg; r < rend; r++) {
        float x = bf2f(X[(long)r * 256 + t]);
        s += x;
        s2 += x * x;
    }
    atomicAdd(&stats[t], s);
    atomicAdd(&stats[256 + t], s2);
}

__global__ __launch_bounds__(256) void bn_stats32(const float* __restrict__ X, float* __restrict__ stats,
                                                  int rows, int RPB) {
    __shared__ float ss[256], ss2[256];
    int t = threadIdx.x, c = t & 31, rs = t >> 5;
    int rbeg = blockIdx.x * RPB;
    int rend = rbeg + RPB;
    if (rend > rows) rend = rows;
    float s = 0.f, s2 = 0.f;
    for (int r = rbeg + rs; r < rend; r += 8) {
        float x = X[(long)r * 32 + c];
        s += x;
        s2 += x * x;
    }
    ss[t] = s;
    ss2[t] = s2;
    __syncthreads();
    if (t < 32) {
        for (int j = 32; j < 256; j += 32) { s += ss[t + j]; s2 += ss2[t + j]; }
        atomicAdd(&stats[c], s);
        atomicAdd(&stats[32 + c], s2);
    }
}

// ---------------- fc2 GEMM with fused bn_apply1(+residual) on A, + fused elr2 ----------------
__global__ __launch_bounds__(256) void gemm_fc2_fused(const u16* __restrict__ rst, const u16* __restrict__ hh,
                                                      const float* __restrict__ stats, const float* __restrict__ g,
                                                      const float* __restrict__ b, const u16* __restrict__ Bsw,
                                                      const float* __restrict__ al2, const float* __restrict__ ar2,
                                                      float* __restrict__ feat2, float* __restrict__ el2,
                                                      float* __restrict__ er2, int M, float invN) {
    __shared__ float sc[256], sh[256];
    __shared__ float tile[64][32];
    const int t = threadIdx.x;
    {
        float mu = stats[t] * invN;
        float var = fmaxf(stats[256 + t] * invN - mu * mu, 0.f);
        float s = g[t] * rsqrtf(var + 1e-5f);
        sc[t] = s;
        sh[t] = b[t] - mu * s;
    }
    __syncthreads();
    const int lane = t & 63, wq = t >> 6;
    const int rb = blockIdx.x * 64;
    const int m = lane & 15, q = lane >> 4;
    const int row = rb + wq * 16 + m;
    short8 a[8];
#pragma unroll
    for (int kb = 0; kb < 8; kb++) {
        if (row < M) {
            int k0 = kb * 32 + q * 8;
            ushort4 r01 = *(const ushort4*)(rst + (size_t)row * 256 + k0);
            ushort4 r23 = *(const ushort4*)(rst + (size_t)row * 256 + k0 + 4);
            ushort4 h01 = *(const ushort4*)(hh + (size_t)row * 256 + k0);
            ushort4 h23 = *(const ushort4*)(hh + (size_t)row * 256 + k0 + 4);
            u16 rv[8] = {r01.x, r01.y, r01.z, r01.w, r23.x, r23.y, r23.z, r23.w};
            u16 hv[8] = {h01.x, h01.y, h01.z, h01.w, h23.x, h23.y, h23.z, h23.w};
            short8 av;
#pragma unroll
            for (int j = 0; j < 8; j++) {
                int c = k0 + j;
                float y = sc[c] * bf2f(rv[j]) + sh[c];
                y = (y > 0.f) ? y : expm1f(y);
                av[j] = (short)f2bf(bf2f(hv[j]) + y);
            }
            a[kb] = av;
        } else a[kb] = (short8){0, 0, 0, 0, 0, 0, 0, 0};
    }
    const short8* B8 = (const short8*)Bsw;
#pragma unroll
    for (int ct = 0; ct < 2; ct++) {
        f32x4 acc = {0.f, 0.f, 0.f, 0.f};
#pragma unroll
        for (int kb = 0; kb < 8; kb++)
            acc = __builtin_amdgcn_mfma_f32_16x16x32_bf16(a[kb], B8[(ct * 8 + kb) * 64 + lane], acc, 0, 0, 0);
#pragma unroll
        for (int r = 0; r < 4; r++) {
            int rl = wq * 16 + q * 4 + r;
            int ro = rb + rl;
            float v = 0.f;
            if (ro < M) {
                v = acc[r];
                feat2[(size_t)ro * 32 + ct * 16 + m] = v;
            }
            tile[rl][ct * 16 + m] = v;
        }
    }
    __syncthreads();
    if (t < 64) {
        int node = rb + t;
        if (node < M) {
            float a_ = 0.f, b_ = 0.f;
#pragma unroll
            for (int d = 0; d < 32; d++) {
                float fv = tile[t][d];
                a_ += fv * al2[d];
                b_ += fv * ar2[d];
            }
            el2[node] = a_;
            er2[node] = b_;
        }
    }
}

// ---------------- agg2: fused edge weights (NO stats fusion) ----------------
__global__ __launch_bounds__(256) void agg2_fused(const float* __restrict__ feat, const float* __restrict__ el,
                                                  const float* __restrict__ er, const int* __restrict__ offs,
                                                  const int* __restrict__ srcs, float* __restrict__ rst,
                                                  int N, int E) {
    const int t = threadIdx.x;
    const int node = blockIdx.x * 8 + (t >> 5);
    const int d = t & 31;
    if (node >= N) return;
    int beg = offs[node], end = offs[node + 1];
    if (beg < 0) beg = 0;
    if (end > E) end = E;
    float ern = er[node];
    float acc = 0.f, sw = 0.f;
#pragma unroll 2
    for (int j = beg; j < end; j++) {
        int s = srcs[j];
        if ((unsigned)s >= (unsigned)N) continue;
        float wv = edgew(el[s] + ern);
        sw += wv;
        acc += wv * feat[(size_t)s * 32 + d];
    }
    rst[(size_t)node * 32 + d] = acc / (sw + 1e-16f);
}

// ---------------- final bn + elu -> f32 out ----------------
__global__ __launch_bounds__(256) void bn_apply2(const float* __restrict__ rst, const float* __restrict__ stats,
                                                 const float* __restrict__ g, const float* __restrict__ b,
                                                 float* __restrict__ out, int total, float invN) {
    int idx = blockIdx.x * 256 + threadIdx.x;
    if (idx >= total) return;
    int c = idx & 31;
    float mu = stats[c] * invN;
    float var = fmaxf(stats[32 + c] * invN - mu * mu, 0.f);
    float y = g[c] * (rst[idx] - mu) * rsqrtf(var + 1e-5f) + b[c];
    y = (y > 0.f) ? y : expm1f(y);
    out[idx] = y;
}

extern "C" void kernel_launch(void* const* d_in, const int* in_sizes, int n_in, void* d_out, int out_size, void* d_ws,
                              size_t ws_size, hipStream_t stream) {
    const int N = out_size / ODIM;
    const int E = in_sizes[2];

    const int* src = (const int*)d_in[2];
    const int* dst = (const int*)d_in[3];
    const float* in_h = (const float*)d_in[0];
    const float* W_emb = (const float*)d_in[4];  const float* b_emb = (const float*)d_in[5];
    const float* fc1 = (const float*)d_in[18];   const float* al1 = (const float*)d_in[19];
    const float* ar1 = (const float*)d_in[20];
    const float* g1 = (const float*)d_in[21];    const float* b1 = (const float*)d_in[22];
    const float* fc2 = (const float*)d_in[23];   const float* al2 = (const float*)d_in[24];
    const float* ar2 = (const float*)d_in[25];
    const float* g2 = (const float*)d_in[26];    const float* b2 = (const float*)d_in[27];
    float* out = (float*)d_out;

    // ---- ws layout (~26 MB) ----
    char* base = (char*)d_ws;
    size_t off = 0;
    auto alloc = [&](size_t bytes) { void* p = base + off; off += (bytes + 63) & ~63ull; return p; };
    char* zb   = (char*)alloc((size_t)N * 4 + 512 * 4 + 64 * 4);
    int* deg   = (int*)zb;
    float* stats  = (float*)(zb + (size_t)N * 4);
    float* stats2 = stats + 512;
    int* offs  = (int*)alloc((size_t)(N + 1) * 4);
    int* cursor = (int*)alloc((size_t)N * 4);
    int* srcs  = (int*)alloc((size_t)E * 4);
    u16* Ah    = (u16*)alloc((size_t)N * 128 * 2);
    u16* Bemb  = (u16*)alloc((size_t)128 * 256 * 2);
    u16* Bfc1  = (u16*)alloc((size_t)256 * 256 * 2);
    u16* Bfc2  = (u16*)alloc((size_t)256 * 32 * 2);
    u16* hh    = (u16*)alloc((size_t)N * HDIM * 2);
    u16* feat1 = (u16*)alloc((size_t)N * HDIM * 2);
    u16* el1   = (u16*)alloc((size_t)N * 8 * 2);
    u16* er1   = (u16*)alloc((size_t)N * 8 * 2);
    u16* rst   = (u16*)alloc((size_t)N * HDIM * 2);
    float* feat2 = (float*)alloc((size_t)N * 32 * 4);
    float* el2 = (float*)alloc((size_t)N * 4);
    float* er2 = (float*)alloc((size_t)N * 4);
    float* rst2 = (float*)alloc((size_t)N * 32 * 4);

    const int NB64 = (N + 63) / 64;

    hipMemsetAsync(zb, 0, (size_t)N * 4 + 512 * 4 + 64 * 4, stream);
    prep_kernel<<<dim3((N * 128 / 4 + 255) / 256, 4), 256, 0, stream>>>(in_h, W_emb, fc1, fc2, Ah, Bemb, Bfc1, Bfc2,
                                                                        N * 128 / 4);
    deg_kernel<<<(E + 255) / 256, 256, 0, stream>>>(dst, deg, E, N);
    scan_kernel<<<1, 256, 0, stream>>>(deg, offs, cursor, N);
    fill_kernel<<<(E + 255) / 256, 256, 0, stream>>>(src, dst, cursor, srcs, E, N);
    gemm_mfma<128, 256, true, u16><<<NB64, 256, 0, stream>>>(Ah, Bemb, b_emb, hh, N);
    gemm_fc1_elr<<<NB64, 256, 0, stream>>>(hh, Bfc1, al1, ar1, feat1, el1, er1, N);
    agg1_fused<<<(N + 3) / 4, 256, 0, stream>>>(feat1, el1, er1, offs, srcs, rst, N, E);
    bn_stats256<<<(N + 39) / 40, 256, 0, stream>>>(rst, stats, N, 40);
    gemm_fc2_fused<<<NB64, 256, 0, stream>>>(rst, hh, stats, g1, b1, Bfc2, al2, ar2, feat2, el2, er2, N, 1.f / N);
    agg2_fused<<<(N + 7) / 8, 256, 0, stream>>>(feat2, el2, er2, offs, srcs, rst2, N, E);
    bn_stats32<<<(N + 63) / 64, 256, 0, stream>>>(rst2, stats2, N, 64);
    bn_apply2<<<(N * ODIM + 255) / 256, 256, 0, stream>>>(rst2, stats2, g2, b2, out, N * ODIM, 1.f / N);
}